// Round 3
// baseline (59.491 us; speedup 1.0000x reference)
//
#include <hip/hip_runtime.h>

// sites [4096,128] f32, consensus [512,128] f32
// out = softmax(-L1dist, axis=-1) -> [4096,512] f32
#define N_SITES 4096
#define M_CONS  512
#define DIM     128
#define NBLOCKS 256

// Single fused kernel. 256 blocks x 512 threads, 96 KB LDS -> exactly
// 1 block/CU on 256 CUs => all blocks co-resident => device-scope atomic
// grid barrier is safe (counter zeroed via hipMemsetAsync each launch).
//
// Phase 1 (dist): block tile 128 rows x 64 cols, split-k x4.
//   wave = (kg 0..3) x (wr 0..1); lane tile 8 rows (8i+lr) x 8 CONSECUTIVE
//   cols (lc*8+j). LDS: sites[128][128] quad-swizzled by (r&7); cons[64][128]
//   quad-swizzled by ((c>>3)&7) -> all compute reads conflict-free.
//   Combine: per row-half, all 4 kg dump [kg][64][64] (quad ^ row&7) into
//   the 64 KB staging area; all 512 threads read 4 partials, sum, and store
//   POSITIVE distance as coalesced float4 (negation folded into softmax).
// Phase 2 (softmax): after grid barrier, block handles 16 rows; wave = 2 rows;
//   lane = 8 consecutive floats; min/sum via __shfl_xor; in-place.
__global__ __launch_bounds__(512, 2) void fused_kernel(const float* __restrict__ sites,
                                                       const float* __restrict__ cons,
                                                       float* __restrict__ out,
                                                       unsigned int* __restrict__ ctr) {
    __shared__ __align__(16) float lds[24576];   // 96 KB
    float* s_sites = lds;                        // [128][128]
    float* s_cons  = lds + 16384;                // [64][128]

    const int tid    = threadIdx.x;
    const int bid    = blockIdx.x;
    const int rowBlk = bid & 31;                 // 0..31
    const int colBlk = bid >> 5;                 // 0..7

    // ---- stage sites (64 KB): quad stored at q ^ (r&7)
    {
        const float* g = sites + (size_t)rowBlk * 128 * DIM;
#pragma unroll
        for (int it = 0; it < 8; it++) {
            int f = tid + it * 512;              // 0..4095
            int r = f >> 5, q = f & 31;
            float4 v = *(const float4*)(g + r * DIM + (q << 2));
            *(float4*)&s_sites[r * DIM + ((q ^ (r & 7)) << 2)] = v;
        }
    }
    // ---- stage cons (32 KB): quad stored at q ^ ((r>>3)&7)
    {
        const float* g = cons + (size_t)colBlk * 64 * DIM;
#pragma unroll
        for (int it = 0; it < 4; it++) {
            int f = tid + it * 512;              // 0..2047
            int r = f >> 5, q = f & 31;
            float4 v = *(const float4*)(g + r * DIM + (q << 2));
            *(float4*)&s_cons[r * DIM + ((q ^ ((r >> 3) & 7)) << 2)] = v;
        }
    }

    const int wave = tid >> 6;
    const int lane = tid & 63;
    const int kg = wave >> 1;                    // k-dims [kg*32, kg*32+32)
    const int wr = wave & 1;                     // rows [wr*64, wr*64+64)
    const int lr = lane >> 3;                    // 0..7
    const int lc = lane & 7;                     // 0..7

    float acc[8][8];
#pragma unroll
    for (int i = 0; i < 8; i++)
#pragma unroll
        for (int j = 0; j < 8; j++) acc[i][j] = 0.f;

    __syncthreads();

    // ---- compute this k-group's 8 k-quads
    const int q0 = kg << 3;
#pragma unroll 2
    for (int qq = 0; qq < 8; qq++) {
        const int q = q0 + qq;
        float4 sv[8], cv[8];
        const int qs_s = (q ^ lr) << 2;          // site row key (r&7)==lr
        const int qs_c = (q ^ lc) << 2;          // cons row key ((c>>3)&7)==lc
#pragma unroll
        for (int i = 0; i < 8; i++)
            sv[i] = *(const float4*)&s_sites[(wr * 64 + 8 * i + lr) * DIM + qs_s];
#pragma unroll
        for (int j = 0; j < 8; j++)
            cv[j] = *(const float4*)&s_cons[(lc * 8 + j) * DIM + qs_c];
#pragma unroll
        for (int i = 0; i < 8; i++) {
#pragma unroll
            for (int j = 0; j < 8; j++) {
                acc[i][j] += fabsf(sv[i].x - cv[j].x);
                acc[i][j] += fabsf(sv[i].y - cv[j].y);
                acc[i][j] += fabsf(sv[i].z - cv[j].z);
                acc[i][j] += fabsf(sv[i].w - cv[j].w);
            }
        }
    }

    // ---- split-k combine + coalesced store, two row-halves through LDS
    for (int h = 0; h < 2; h++) {
        __syncthreads();                         // staging / previous half free
        if (wr == h) {
            float* base = lds + kg * 4096;       // [kg][64 rows][16 quads]
#pragma unroll
            for (int i = 0; i < 8; i++) {
                int r64 = 8 * i + lr;
                float4 v0 = { acc[i][0], acc[i][1], acc[i][2], acc[i][3] };
                float4 v1 = { acc[i][4], acc[i][5], acc[i][6], acc[i][7] };
                *(float4*)&base[r64 * 64 + (((lc * 2 + 0) ^ lr) << 2)] = v0;
                *(float4*)&base[r64 * 64 + (((lc * 2 + 1) ^ lr) << 2)] = v1;
            }
        }
        __syncthreads();
#pragma unroll
        for (int oo = 0; oo < 2; oo++) {
            int o = tid + oo * 512;              // 0..1023 = 64 rows x 16 quads
            int r64 = o >> 4;
            int qd  = o & 15;
            const float* b0 = lds + r64 * 64 + ((qd ^ (r64 & 7)) << 2);
            float4 a = *(const float4*)(b0);
            float4 b = *(const float4*)(b0 + 4096);
            float4 c = *(const float4*)(b0 + 8192);
            float4 d = *(const float4*)(b0 + 12288);
            float4 s = { (a.x + b.x) + (c.x + d.x),
                         (a.y + b.y) + (c.y + d.y),
                         (a.z + b.z) + (c.z + d.z),
                         (a.w + b.w) + (c.w + d.w) };
            int grow = rowBlk * 128 + h * 64 + r64;
            int gcol = colBlk * 64 + (qd << 2);
            *(float4*)&out[(size_t)grow * M_CONS + gcol] = s;   // positive dist
        }
    }

    // ---- grid barrier (all 256 blocks co-resident; ctr zeroed per launch)
    __syncthreads();                             // drains vmcnt before barrier
    if (tid == 0) {
        __hip_atomic_fetch_add(ctr, 1u, __ATOMIC_RELEASE, __HIP_MEMORY_SCOPE_AGENT);
        while (__hip_atomic_load(ctr, __ATOMIC_ACQUIRE, __HIP_MEMORY_SCOPE_AGENT) < NBLOCKS) {
            __builtin_amdgcn_s_sleep(2);
        }
    }
    __syncthreads();

    // ---- phase 2: softmax(-d) = exp(min(d)-d)/sum, 16 rows/block, 2 rows/wave
#pragma unroll
    for (int rr = 0; rr < 2; rr++) {
        int row = bid * 16 + wave * 2 + rr;
        float* p = out + (size_t)row * M_CONS + lane * 8;
        float4 v0 = *(const float4*)p;
        float4 v1 = *(const float4*)(p + 4);
        float mn = fminf(fminf(fminf(v0.x, v0.y), fminf(v0.z, v0.w)),
                         fminf(fminf(v1.x, v1.y), fminf(v1.z, v1.w)));
#pragma unroll
        for (int off = 32; off > 0; off >>= 1) mn = fminf(mn, __shfl_xor(mn, off));
        float e[8];
        e[0] = __expf(mn - v0.x); e[1] = __expf(mn - v0.y);
        e[2] = __expf(mn - v0.z); e[3] = __expf(mn - v0.w);
        e[4] = __expf(mn - v1.x); e[5] = __expf(mn - v1.y);
        e[6] = __expf(mn - v1.z); e[7] = __expf(mn - v1.w);
        float s = ((e[0] + e[1]) + (e[2] + e[3])) + ((e[4] + e[5]) + (e[6] + e[7]));
#pragma unroll
        for (int off = 32; off > 0; off >>= 1) s += __shfl_xor(s, off);
        const float inv = 1.f / s;
        float4 o0 = { e[0] * inv, e[1] * inv, e[2] * inv, e[3] * inv };
        float4 o1 = { e[4] * inv, e[5] * inv, e[6] * inv, e[7] * inv };
        *(float4*)p       = o0;
        *(float4*)(p + 4) = o1;
    }
}

extern "C" void kernel_launch(void* const* d_in, const int* in_sizes, int n_in,
                              void* d_out, int out_size, void* d_ws, size_t ws_size,
                              hipStream_t stream) {
    const float* sites = (const float*)d_in[0];
    const float* cons  = (const float*)d_in[1];
    float* out = (float*)d_out;
    unsigned int* ctr = (unsigned int*)d_ws;

    hipMemsetAsync(ctr, 0, sizeof(unsigned int), stream);   // barrier counter = 0
    fused_kernel<<<NBLOCKS, 512, 0, stream>>>(sites, cons, out, ctr);
}

// Round 4
// 33.485 us; speedup vs baseline: 1.7767x; 1.7767x over previous
//
#include <hip/hip_runtime.h>

// sites [4096,128] f32, consensus [512,128] f32
// out = softmax(-L1dist, axis=-1) -> [4096,512] f32
#define N_SITES 4096
#define M_CONS  512
#define DIM     128

// K1: negated L1 distance. Grid 64x8 = 512 blocks (2 per CU), 256 threads.
// Block tile 64 rows x 64 cols, in-block split-k x4: wave kg covers k-dims
// [kg*32, kg*32+32) over the whole tile. Lane: 8 rows (8i+lr) x 8 consecutive
// cols (lc*8+j), acc[8][8].
// LDS 64 KB: sites[64][128] quad-swizzled by (r&7), cons[64][128] quad-swizzled
// by ((r>>3)&7) -> all staging and compute accesses conflict-free.
// Combine: reuse the same 64 KB as [kg][64 rows][16 quads ^ (r&7)]; all 256
// threads sum 4 partials and store -dist as coalesced float4.
__global__ __launch_bounds__(256, 2) void dist_kernel(const float* __restrict__ sites,
                                                      const float* __restrict__ cons,
                                                      float* __restrict__ out) {
    __shared__ __align__(16) float lds[16384];   // 64 KB
    float* s_sites = lds;                        // [64][128]
    float* s_cons  = lds + 8192;                 // [64][128]

    const int tid    = threadIdx.x;
    const int rowBlk = blockIdx.x;               // 0..63
    const int colBlk = blockIdx.y;               // 0..7

    // ---- stage sites tile (32 KB): quad stored at q ^ (r&7)
    {
        const float* g = sites + (size_t)rowBlk * 64 * DIM;
#pragma unroll
        for (int it = 0; it < 8; it++) {
            int f = tid + it * 256;              // 0..2047
            int r = f >> 5, q = f & 31;
            float4 v = *(const float4*)(g + r * DIM + (q << 2));
            *(float4*)&s_sites[r * DIM + ((q ^ (r & 7)) << 2)] = v;
        }
    }
    // ---- stage cons tile (32 KB): quad stored at q ^ ((r>>3)&7)
    {
        const float* g = cons + (size_t)colBlk * 64 * DIM;
#pragma unroll
        for (int it = 0; it < 8; it++) {
            int f = tid + it * 256;              // 0..2047
            int r = f >> 5, q = f & 31;
            float4 v = *(const float4*)(g + r * DIM + (q << 2));
            *(float4*)&s_cons[r * DIM + ((q ^ ((r >> 3) & 7)) << 2)] = v;
        }
    }

    const int kg   = tid >> 6;                   // wave = k-group, dims [kg*32,..+32)
    const int lane = tid & 63;
    const int lr   = lane >> 3;                  // 0..7
    const int lc   = lane & 7;                   // 0..7

    float acc[8][8];
#pragma unroll
    for (int i = 0; i < 8; i++)
#pragma unroll
        for (int j = 0; j < 8; j++) acc[i][j] = 0.f;

    __syncthreads();

    // ---- compute this k-group's 8 k-quads.
    // cv[8] loaded once per quad; sites streamed one row at a time so the
    // live set stays ~(acc 64 + cv 32 + sv 4) VGPRs and each row's 128 VALU
    // ops depend on a single outstanding ds_read.
    const int q0 = kg << 3;
    for (int qq = 0; qq < 8; qq++) {
        const int q = q0 + qq;
        float4 cv[8];
        const int qs_c = (q ^ lc) << 2;          // cons rows of this lane: (r>>3)==lc
#pragma unroll
        for (int j = 0; j < 8; j++)
            cv[j] = *(const float4*)&s_cons[(lc * 8 + j) * DIM + qs_c];
        const int qs_s = (q ^ lr) << 2;          // site rows of this lane: (r&7)==lr
#pragma unroll
        for (int i = 0; i < 8; i++) {
            float4 sv = *(const float4*)&s_sites[(8 * i + lr) * DIM + qs_s];
#pragma unroll
            for (int j = 0; j < 8; j++) {
                acc[i][j] += fabsf(sv.x - cv[j].x);
                acc[i][j] += fabsf(sv.y - cv[j].y);
                acc[i][j] += fabsf(sv.z - cv[j].z);
                acc[i][j] += fabsf(sv.w - cv[j].w);
            }
        }
    }

    __syncthreads();                             // staging space now free

    // ---- dump partials: [kg][64 rows][16 quads], quad ^ (r&7)
    {
        float* base = lds + kg * 4096;
#pragma unroll
        for (int i = 0; i < 8; i++) {
            int r = 8 * i + lr;
            float4 v0 = { acc[i][0], acc[i][1], acc[i][2], acc[i][3] };
            float4 v1 = { acc[i][4], acc[i][5], acc[i][6], acc[i][7] };
            *(float4*)&base[r * 64 + (((lc * 2 + 0) ^ (r & 7)) << 2)] = v0;
            *(float4*)&base[r * 64 + (((lc * 2 + 1) ^ (r & 7)) << 2)] = v1;
        }
    }
    __syncthreads();

    // ---- all 256 threads: sum 4 partials, negate, coalesced float4 store
    const int grow0 = rowBlk * 64;
    const int gcol0 = colBlk * 64;
#pragma unroll
    for (int oo = 0; oo < 4; oo++) {
        int o  = tid + oo * 256;                 // 0..1023 = 64 rows x 16 quads
        int r  = o >> 4;
        int qd = o & 15;
        const float* b0 = lds + r * 64 + ((qd ^ (r & 7)) << 2);
        float4 a = *(const float4*)(b0);
        float4 b = *(const float4*)(b0 + 4096);
        float4 c = *(const float4*)(b0 + 8192);
        float4 d = *(const float4*)(b0 + 12288);
        float4 s = { -((a.x + b.x) + (c.x + d.x)),
                     -((a.y + b.y) + (c.y + d.y)),
                     -((a.z + b.z) + (c.z + d.z)),
                     -((a.w + b.w) + (c.w + d.w)) };
        *(float4*)&out[(size_t)(grow0 + r) * M_CONS + gcol0 + (qd << 2)] = s;
    }
}

// K2: in-place row softmax over M_CONS=512. One wave per row, 8 f32/lane.
__global__ __launch_bounds__(256) void softmax_kernel(float* __restrict__ out) {
    const int row  = blockIdx.x * 4 + (threadIdx.x >> 6);
    const int lane = threadIdx.x & 63;
    float* p = out + (size_t)row * M_CONS + lane * 8;

    float4 v0 = *(const float4*)p;
    float4 v1 = *(const float4*)(p + 4);

    float m = fmaxf(fmaxf(fmaxf(v0.x, v0.y), fmaxf(v0.z, v0.w)),
                    fmaxf(fmaxf(v1.x, v1.y), fmaxf(v1.z, v1.w)));
#pragma unroll
    for (int off = 32; off > 0; off >>= 1) m = fmaxf(m, __shfl_xor(m, off));

    float e[8];
    e[0] = __expf(v0.x - m); e[1] = __expf(v0.y - m);
    e[2] = __expf(v0.z - m); e[3] = __expf(v0.w - m);
    e[4] = __expf(v1.x - m); e[5] = __expf(v1.y - m);
    e[6] = __expf(v1.z - m); e[7] = __expf(v1.w - m);

    float s = ((e[0] + e[1]) + (e[2] + e[3])) + ((e[4] + e[5]) + (e[6] + e[7]));
#pragma unroll
    for (int off = 32; off > 0; off >>= 1) s += __shfl_xor(s, off);

    const float inv = 1.f / s;
    float4 o0 = { e[0] * inv, e[1] * inv, e[2] * inv, e[3] * inv };
    float4 o1 = { e[4] * inv, e[5] * inv, e[6] * inv, e[7] * inv };
    *(float4*)p       = o0;
    *(float4*)(p + 4) = o1;
}

extern "C" void kernel_launch(void* const* d_in, const int* in_sizes, int n_in,
                              void* d_out, int out_size, void* d_ws, size_t ws_size,
                              hipStream_t stream) {
    const float* sites = (const float*)d_in[0];
    const float* cons  = (const float*)d_in[1];
    float* out = (float*)d_out;

    dim3 g1(N_SITES / 64, M_CONS / 64);          // 64 x 8 = 512 blocks, 2/CU
    dist_kernel<<<g1, 256, 0, stream>>>(sites, cons, out);

    softmax_kernel<<<N_SITES / 4, 256, 0, stream>>>(out);
}